// Round 7
// baseline (136.049 us; speedup 1.0000x reference)
//
#include <hip/hip_runtime.h>
#include <hip/hip_bf16.h>

#define NPTS   131072
#define NNODES 2048
#define KSEL   32

// ---- knn decomposition ----
#define TKNN   256                 // threads per knn block
#define PPT    4                   // points per thread (ILP chains per s_load)
#define PPG_K  (TKNN * PPT)        // 1024 points per knn group
#define NGRP_K (NPTS / PPG_K)      // 128 knn groups
#define NCHUNK 16                  // node chunks (block-uniform -> s_load)
#define CHN    (NNODES / NCHUNK)   // 128 nodes per chunk

// ---- grouping/scatter decomposition (independent of knn's) ----
#define GSZ    512                 // points per stability group
#define NG     (NPTS / GSZ)        // 256 groups

typedef unsigned int uint;
typedef unsigned short u16;
typedef unsigned long long u64;

// order-preserving fp32 -> u32 (handles tiny-negative cancellation results)
__device__ __forceinline__ uint f2ord(float d) {
    uint b = __float_as_uint(d);
    return (b & 0x80000000u) ? ~b : (b | 0x80000000u);
}
__device__ __forceinline__ float ord2f(uint t) {
    uint b = (t & 0x80000000u) ? (t ^ 0x80000000u) : ~t;
    return __uint_as_float(b);
}

// --- K0: init knnres to max keys; first 2048 threads also pack nodes {x,y,z,|n|^2} ---
__global__ __launch_bounds__(256) void prep_init(const float* __restrict__ nodes,
                                                 float4* __restrict__ n4,
                                                 u64* __restrict__ knnres) {
    int i = blockIdx.x * 256 + threadIdx.x;
    knnres[i] = ~0ull;
    if (i < NNODES) {
        float x = nodes[3 * i], y = nodes[3 * i + 1], z = nodes[3 * i + 2];
        // |n|^2 with numpy's mul-then-add rounding
        float nn = __fadd_rn(__fadd_rn(__fmul_rn(x, x), __fmul_rn(y, y)), __fmul_rn(z, z));
        n4[i] = make_float4(x, y, z, nn);
    }
}

// --- K1: partial 1-NN, 4 pts/thread; chunks merge via u64 atomicMin (d2, idx) key ---
// d2 = (pp + r) + nn, r = fma(-2p2,z, fma(-2p1,y, (-2p0)*x)) == -(2*dot) bit-exactly
// (x -2 is exact each step), matching ref (pp - 2*dot) + nn, dot = fma-chain ascending k.
__global__ __launch_bounds__(256) void knn_part(const float* __restrict__ pts,
                                                const float4* __restrict__ n4,
                                                u64* __restrict__ knnres) {
    int bid = blockIdx.x;
    int c   = bid & (NCHUNK - 1);            // block-uniform chunk
    int g   = bid >> 4;                      // knn point group
    int t   = threadIdx.x;

    float pp[PPT], nx[PPT], ny[PPT], nz[PPT];
    #pragma unroll
    for (int q = 0; q < PPT; ++q) {
        int pid = g * PPG_K + q * TKNN + t;
        float p0 = pts[3 * pid], p1 = pts[3 * pid + 1], p2 = pts[3 * pid + 2];
        pp[q] = __fadd_rn(__fadd_rn(__fmul_rn(p0, p0), __fmul_rn(p1, p1)), __fmul_rn(p2, p2));
        nx[q] = __fmul_rn(-2.0f, p0);        // exact
        ny[q] = __fmul_rn(-2.0f, p1);
        nz[q] = __fmul_rn(-2.0f, p2);
    }

    const float4* np = n4 + c * CHN;         // block-uniform base -> scalar s_load
    float best[PPT];
    int   bi[PPT];
    #pragma unroll
    for (int q = 0; q < PPT; ++q) { best[q] = 3.4e38f; bi[q] = 0; }

    #pragma unroll 8
    for (int jj = 0; jj < CHN; ++jj) {
        float4 v = np[jj];
        #pragma unroll
        for (int q = 0; q < PPT; ++q) {
            float r = __fmaf_rn(nz[q], v.z, __fmaf_rn(ny[q], v.y, __fmul_rn(nx[q], v.x)));
            float d = __fadd_rn(__fadd_rn(pp[q], r), v.w);
            if (d < best[q]) { best[q] = d; bi[q] = jj; }  // strict <: first occurrence
        }
    }

    #pragma unroll
    for (int q = 0; q < PPT; ++q) {
        int pid = g * PPG_K + q * TKNN + t;
        u64 key = ((u64)f2ord(best[q]) << 32) | (uint)(c * CHN + bi[q]);
        atomicMin(&knnres[pid], key);        // min key == (min d2, then min node idx)
    }
}

// --- K2: decode winners, write d2/id/pcd, per-group u16 histogram, zero patch ---
// grid = NG(256) x 256; group = 512 consecutive points.
__global__ __launch_bounds__(256) void merge_hist(const u64* __restrict__ knnres,
                                                  float* __restrict__ out_d2,
                                                  float* __restrict__ out_id,
                                                  int* __restrict__ pcd,
                                                  u16* __restrict__ hist16,
                                                  float* __restrict__ patch) {
    __shared__ uint lh[NNODES];
    int g = blockIdx.x, t = threadIdx.x;
    patch[(size_t)g * 256 + t] = 0.0f;       // 256x256 = full 65536-float patch zeroed
    for (int i = t; i < NNODES; i += 256) lh[i] = 0;
    __syncthreads();

    #pragma unroll
    for (int q = 0; q < GSZ / 256; ++q) {
        int pid = g * GSZ + q * 256 + t;
        u64 key = knnres[pid];
        uint bi = (uint)key;                 // low 32: node index
        float d = ord2f((uint)(key >> 32));  // exact d2 decode
        atomicAdd(&lh[bi], 1u);
        out_d2[pid] = d;
        out_id[pid] = (float)bi;             // exact: bi < 2^24
        pcd[pid]    = (int)bi;
    }
    __syncthreads();
    for (int i = t; i < NNODES; i += 256)
        hist16[(size_t)g * NNODES + i] = (u16)lh[i];   // contiguous stores
}

// --- K3: per-node exclusive prefix across the 256 groups; offs in [node][group] ---
// 512 blocks x 256 thr = 4 waves; wave wv -> node bid*4+wv; lane l -> groups 4l..4l+3.
__global__ __launch_bounds__(256) void scan_offs(const u16* __restrict__ hist16,
                                                 uint* __restrict__ offs) {
    int t = threadIdx.x, lane = t & 63, wv = t >> 6;
    int node = blockIdx.x * 4 + wv;

    uint v0 = hist16[(size_t)(4 * lane + 0) * NNODES + node];
    uint v1 = hist16[(size_t)(4 * lane + 1) * NNODES + node];
    uint v2 = hist16[(size_t)(4 * lane + 2) * NNODES + node];
    uint v3 = hist16[(size_t)(4 * lane + 3) * NNODES + node];
    uint s = v0 + v1 + v2 + v3;
    uint a = s;
    #pragma unroll
    for (int d = 1; d < 64; d <<= 1) {
        uint y = __shfl_up(a, d, 64);
        if (lane >= d) a += y;
    }
    uint base = a - s;                        // exclusive across lanes
    uint4 o = make_uint4(base, base + v0, base + v0 + v1, base + v0 + v1 + v2);
    *(uint4*)(offs + (size_t)node * NG + 4 * lane) = o;   // contiguous 16B store
}

// --- K4: stable scatter of first-32 point indices per node ---
__global__ __launch_bounds__(256) void scatter_patch(const int* __restrict__ pcd,
                                                     const uint* __restrict__ offs,
                                                     float* __restrict__ patch) {
    __shared__ int ids[GSZ];
    int g = blockIdx.x, t = threadIdx.x;
    ids[t]       = pcd[g * GSZ + t];
    ids[256 + t] = pcd[g * GSZ + 256 + t];
    __syncthreads();

    int i0 = t, i1 = 256 + t;
    int my0 = ids[i0], my1 = ids[i1];
    int r0 = 0, r1 = 0;
    #pragma unroll 8
    for (int j = 0; j < GSZ; ++j) {
        int id = ids[j];                      // broadcast LDS read, conflict-free
        r0 += (j < i0 && id == my0) ? 1 : 0;
        r1 += (j < i1 && id == my1) ? 1 : 0;
    }
    uint rk0 = offs[(size_t)my0 * NG + g] + (uint)r0;
    uint rk1 = offs[(size_t)my1 * NG + g] + (uint)r1;
    if (rk0 < KSEL) patch[(size_t)my0 * KSEL + rk0] = (float)(g * GSZ + i0);
    if (rk1 < KSEL) patch[(size_t)my1 * KSEL + rk1] = (float)(g * GSZ + i1);
}

extern "C" void kernel_launch(void* const* d_in, const int* in_sizes, int n_in,
                              void* d_out, int out_size, void* d_ws, size_t ws_size,
                              hipStream_t stream) {
    const float* pts   = (const float*)d_in[0];
    const float* nodes = (const float*)d_in[1];

    float* out       = (float*)d_out;
    float* out_d2    = out;                  // 131072 floats
    float* out_id    = out + NPTS;           // 131072 floats
    float* out_patch = out + 2 * NPTS;       // 65536 floats

    // workspace: 4.6 MB
    char* ws = (char*)d_ws;
    u64*   knnres = (u64*) ws;                               // 1 MB   (131072 x u64)
    u16*   hist16 = (u16*) (ws + (1 << 20));                 // 1 MB   (256 x 2048 u16)
    uint*  offs   = (uint*) (ws + (2 << 20));                // 2 MB   (2048 x 256 u32)
    int*   pcd    = (int*)  (ws + (4 << 20));                // 512 KB
    float4* n4    = (float4*)(ws + (4 << 20) + (512 << 10)); // 32 KB

    prep_init<<<NPTS / 256, 256, 0, stream>>>(nodes, n4, knnres);
    knn_part<<<NGRP_K * NCHUNK, TKNN, 0, stream>>>(pts, n4, knnres);
    merge_hist<<<NG, 256, 0, stream>>>(knnres, out_d2, out_id, pcd, hist16, out_patch);
    scan_offs<<<NNODES / 4, 256, 0, stream>>>(hist16, offs);
    scatter_patch<<<NG, 256, 0, stream>>>(pcd, offs, out_patch);
}

// Round 8
// 129.693 us; speedup vs baseline: 1.0490x; 1.0490x over previous
//
#include <hip/hip_runtime.h>
#include <hip/hip_bf16.h>

#define NPTS   131072
#define NNODES 2048
#define KSEL   32

// ---- knn decomposition ----
#define TKNN   256                 // threads per knn block
#define PPT    4                   // points per thread = 2 packed f32x2 chains
#define PPG_K  (TKNN * PPT)        // 1024 points per knn group
#define NGRP_K (NPTS / PPG_K)      // 128 knn groups
#define NCHUNK 16                  // node chunks (block-uniform -> s_load)
#define CHN    (NNODES / NCHUNK)   // 128 nodes per chunk

// ---- grouping/scatter decomposition ----
#define GSZ    512                 // points per stability group
#define NG     (NPTS / GSZ)        // 256 groups

typedef unsigned int uint;
typedef unsigned short u16;
typedef unsigned long long u64;
typedef float f2 __attribute__((ext_vector_type(2)));

__device__ __forceinline__ f2 splat(float s) { return (f2){s, s}; }

// order-preserving fp32 -> u32 (handles tiny-negative cancellation results)
__device__ __forceinline__ uint f2ord(float d) {
    uint b = __float_as_uint(d);
    return (b & 0x80000000u) ? ~b : (b | 0x80000000u);
}
__device__ __forceinline__ float ord2f(uint t) {
    uint b = (t & 0x80000000u) ? (t ^ 0x80000000u) : ~t;
    return __uint_as_float(b);
}

// --- K0: init knnres to max keys; first 2048 threads also pack nodes {x,y,z,|n|^2} ---
__global__ __launch_bounds__(256) void prep_init(const float* __restrict__ nodes,
                                                 float4* __restrict__ n4,
                                                 u64* __restrict__ knnres) {
    int i = blockIdx.x * 256 + threadIdx.x;
    knnres[i] = ~0ull;
    if (i < NNODES) {
        float x = nodes[3 * i], y = nodes[3 * i + 1], z = nodes[3 * i + 2];
        // |n|^2 with numpy's mul-then-add rounding
        float nn = __fadd_rn(__fadd_rn(__fmul_rn(x, x), __fmul_rn(y, y)), __fmul_rn(z, z));
        n4[i] = make_float4(x, y, z, nn);
    }
}

// --- K1: partial 1-NN, 4 pts/thread as 2 packed-f32 chains (v_pk_* VOP3P) ---
// Per half: m = nx*x; t = fma(ny,y,m); r = fma(nz,z,t); d = (pp + r) + nn
// == reference (pp - 2*dot) + nn bit-exactly (n* = -2*p* exact; pk ops are IEEE-rn;
// lone fmul feeds llvm.fma addend so -ffp-contract cannot refuse/refuse... cannot fuse;
// plain fadds have no fmul partner). Strict < ascending jj = first-occurrence argmin.
__global__ __launch_bounds__(256) void knn_part(const float* __restrict__ pts,
                                                const float4* __restrict__ n4,
                                                u64* __restrict__ knnres) {
    int bid = blockIdx.x;
    int c   = bid & (NCHUNK - 1);            // block-uniform chunk
    int g   = bid >> 4;                      // knn point group
    int t   = threadIdx.x;

    // load 4 points, pack into 2 chains: chain q holds points (2q, 2q+1)
    f2 pp2[2], nx2[2], ny2[2], nz2[2];
    #pragma unroll
    for (int q = 0; q < 2; ++q) {
        #pragma unroll
        for (int h = 0; h < 2; ++h) {
            int pid = g * PPG_K + (2 * q + h) * TKNN + t;
            float p0 = pts[3 * pid], p1 = pts[3 * pid + 1], p2 = pts[3 * pid + 2];
            float pp = __fadd_rn(__fadd_rn(__fmul_rn(p0, p0), __fmul_rn(p1, p1)),
                                 __fmul_rn(p2, p2));
            pp2[q][h] = pp;
            nx2[q][h] = __fmul_rn(-2.0f, p0);   // exact
            ny2[q][h] = __fmul_rn(-2.0f, p1);
            nz2[q][h] = __fmul_rn(-2.0f, p2);
        }
    }

    const float4* np = n4 + c * CHN;         // block-uniform base -> scalar s_load
    float best[PPT];
    int   bi[PPT];
    #pragma unroll
    for (int q = 0; q < PPT; ++q) { best[q] = 3.4e38f; bi[q] = 0; }

    #pragma unroll 8
    for (int jj = 0; jj < CHN; ++jj) {
        float4 v = np[jj];                   // s_load_dwordx4 batches
        #pragma unroll
        for (int q = 0; q < 2; ++q) {
            f2 m = nx2[q] * splat(v.x);                      // v_pk_mul_f32
            f2 r = __builtin_elementwise_fma(ny2[q], splat(v.y), m);   // v_pk_fma_f32
            r    = __builtin_elementwise_fma(nz2[q], splat(v.z), r);   // v_pk_fma_f32
            f2 d = (pp2[q] + r) + splat(v.w);                // 2x v_pk_add_f32
            if (d.x < best[2*q])   { best[2*q]   = d.x; bi[2*q]   = jj; }
            if (d.y < best[2*q+1]) { best[2*q+1] = d.y; bi[2*q+1] = jj; }
        }
    }

    #pragma unroll
    for (int h = 0; h < PPT; ++h) {
        int pid = g * PPG_K + h * TKNN + t;
        u64 key = ((u64)f2ord(best[h]) << 32) | (uint)(c * CHN + bi[h]);
        atomicMin(&knnres[pid], key);        // min key == (min d2, then min node idx)
    }
}

// --- K2: decode winners, write d2/id/pcd, per-group u16 histogram, zero patch ---
__global__ __launch_bounds__(256) void merge_hist(const u64* __restrict__ knnres,
                                                  float* __restrict__ out_d2,
                                                  float* __restrict__ out_id,
                                                  int* __restrict__ pcd,
                                                  u16* __restrict__ hist16,
                                                  float* __restrict__ patch) {
    __shared__ uint lh[NNODES];
    int g = blockIdx.x, t = threadIdx.x;
    patch[(size_t)g * 256 + t] = 0.0f;       // 256x256 = full 65536-float patch zeroed
    for (int i = t; i < NNODES; i += 256) lh[i] = 0;
    __syncthreads();

    #pragma unroll
    for (int q = 0; q < GSZ / 256; ++q) {
        int pid = g * GSZ + q * 256 + t;
        u64 key = knnres[pid];
        uint bi = (uint)key;                 // low 32: node index
        float d = ord2f((uint)(key >> 32));  // exact d2 decode
        atomicAdd(&lh[bi], 1u);
        out_d2[pid] = d;
        out_id[pid] = (float)bi;             // exact: bi < 2^24
        pcd[pid]    = (int)bi;
    }
    __syncthreads();
    for (int i = t; i < NNODES; i += 256)
        hist16[(size_t)g * NNODES + i] = (u16)lh[i];   // contiguous stores
}

// --- K3: per-node exclusive prefix across the 256 groups; offs in [node][group] ---
__global__ __launch_bounds__(256) void scan_offs(const u16* __restrict__ hist16,
                                                 uint* __restrict__ offs) {
    int t = threadIdx.x, lane = t & 63, wv = t >> 6;
    int node = blockIdx.x * 4 + wv;

    uint v0 = hist16[(size_t)(4 * lane + 0) * NNODES + node];
    uint v1 = hist16[(size_t)(4 * lane + 1) * NNODES + node];
    uint v2 = hist16[(size_t)(4 * lane + 2) * NNODES + node];
    uint v3 = hist16[(size_t)(4 * lane + 3) * NNODES + node];
    uint s = v0 + v1 + v2 + v3;
    uint a = s;
    #pragma unroll
    for (int d = 1; d < 64; d <<= 1) {
        uint y = __shfl_up(a, d, 64);
        if (lane >= d) a += y;
    }
    uint base = a - s;                        // exclusive across lanes
    uint4 o = make_uint4(base, base + v0, base + v0 + v1, base + v0 + v1 + v2);
    *(uint4*)(offs + (size_t)node * NG + 4 * lane) = o;   // contiguous 16B store
}

// --- K4: stable scatter of first-32 point indices per node ---
__global__ __launch_bounds__(256) void scatter_patch(const int* __restrict__ pcd,
                                                     const uint* __restrict__ offs,
                                                     float* __restrict__ patch) {
    __shared__ int ids[GSZ];
    int g = blockIdx.x, t = threadIdx.x;
    ids[t]       = pcd[g * GSZ + t];
    ids[256 + t] = pcd[g * GSZ + 256 + t];
    __syncthreads();

    int i0 = t, i1 = 256 + t;
    int my0 = ids[i0], my1 = ids[i1];
    int r0 = 0, r1 = 0;
    #pragma unroll 8
    for (int j = 0; j < GSZ; ++j) {
        int id = ids[j];                      // broadcast LDS read, conflict-free
        r0 += (j < i0 && id == my0) ? 1 : 0;
        r1 += (j < i1 && id == my1) ? 1 : 0;
    }
    uint rk0 = offs[(size_t)my0 * NG + g] + (uint)r0;
    uint rk1 = offs[(size_t)my1 * NG + g] + (uint)r1;
    if (rk0 < KSEL) patch[(size_t)my0 * KSEL + rk0] = (float)(g * GSZ + i0);
    if (rk1 < KSEL) patch[(size_t)my1 * KSEL + rk1] = (float)(g * GSZ + i1);
}

extern "C" void kernel_launch(void* const* d_in, const int* in_sizes, int n_in,
                              void* d_out, int out_size, void* d_ws, size_t ws_size,
                              hipStream_t stream) {
    const float* pts   = (const float*)d_in[0];
    const float* nodes = (const float*)d_in[1];

    float* out       = (float*)d_out;
    float* out_d2    = out;                  // 131072 floats
    float* out_id    = out + NPTS;           // 131072 floats
    float* out_patch = out + 2 * NPTS;       // 65536 floats

    // workspace: 4.6 MB
    char* ws = (char*)d_ws;
    u64*   knnres = (u64*) ws;                               // 1 MB   (131072 x u64)
    u16*   hist16 = (u16*) (ws + (1 << 20));                 // 1 MB   (256 x 2048 u16)
    uint*  offs   = (uint*) (ws + (2 << 20));                // 2 MB   (2048 x 256 u32)
    int*   pcd    = (int*)  (ws + (4 << 20));                // 512 KB
    float4* n4    = (float4*)(ws + (4 << 20) + (512 << 10)); // 32 KB

    prep_init<<<NPTS / 256, 256, 0, stream>>>(nodes, n4, knnres);
    knn_part<<<NGRP_K * NCHUNK, TKNN, 0, stream>>>(pts, n4, knnres);
    merge_hist<<<NG, 256, 0, stream>>>(knnres, out_d2, out_id, pcd, hist16, out_patch);
    scan_offs<<<NNODES / 4, 256, 0, stream>>>(hist16, offs);
    scatter_patch<<<NG, 256, 0, stream>>>(pcd, offs, out_patch);
}